// Round 22
// baseline (145.193 us; speedup 1.0000x reference)
//
#include <hip/hip_runtime.h>
#include <stdint.h>

#define K_DIM 1024
#define N_DIM 1024
#define BM 128
#define BN 256
#define BK 32
#define NT (K_DIM / BK)             // 32 K-tiles
#define AOFF_U32 (BM * 16)          // A region: 128 rows x 16 u32
#define UNIT_U32 ((BM + BN) * 16)   // 24 KB per ring unit
#define NRING 3                     // 72 KB -> 2 blocks/CU

#define AS1 __attribute__((address_space(1)))
#define AS3 __attribute__((address_space(3)))

typedef __attribute__((ext_vector_type(4))) float f32x4;
typedef __attribute__((ext_vector_type(8))) short bf16x8;
typedef __attribute__((ext_vector_type(4))) uint32_t u32x4;

// round-half-up to bf16, pack two: low 16 = a, high 16 = b
__device__ __forceinline__ uint32_t pack_bf16(float a, float b) {
  uint32_t ua = __builtin_bit_cast(uint32_t, a) + 0x8000u;
  uint32_t ub = __builtin_bit_cast(uint32_t, b) + 0x8000u;
  return __builtin_amdgcn_perm(ub, ua, 0x07060302u);
}

__device__ __forceinline__ float wbin1(float v, float kkv, float aav) {
  float t = v * kkv;
  t = fminf(fmaxf(t, -1.0f), 1.0f);
  return t * aav;
}

// ---------------- kernel 1: w_bin = bf16(aa*clamp(kk*w,-1,1)) into ws ------
__global__ __launch_bounds__(256) void wconv(const float* __restrict__ w,
                                             const float* __restrict__ kkp,
                                             const float* __restrict__ aap,
                                             uint32_t* __restrict__ wb) {
  const float kkv = kkp[0];
  const float aav = aap[0];
  const int g = blockIdx.x * 256 + threadIdx.x;  // 16 floats per thread
  const f32x4* src = (const f32x4*)(w + (size_t)g * 16);
  f32x4 v0 = src[0], v1 = src[1], v2 = src[2], v3 = src[3];
  uint32_t p[8];
#pragma unroll
  for (int i = 0; i < 4; ++i) {
    f32x4 v = i == 0 ? v0 : (i == 1 ? v1 : (i == 2 ? v2 : v3));
    p[2 * i] = pack_bf16(wbin1(v[0], kkv, aav), wbin1(v[1], kkv, aav));
    p[2 * i + 1] = pack_bf16(wbin1(v[2], kkv, aav), wbin1(v[3], kkv, aav));
  }
  u32x4* dst = (u32x4*)(wb + (size_t)g * 8);
  dst[0] = u32x4{p[0], p[1], p[2], p[3]};
  dst[1] = u32x4{p[4], p[5], p[6], p[7]};
}

// ---------------- kernel 2: fused-convert ring-3, deep-A free-run GEMM -----
// Session champion (R16) with s_setprio REMOVED (A/B probe: T5 is
// structure-conditional, ~0/negative on non-phase-split free-run GEMM per
// m190; never isolated in this session). Everything else byte-identical:
// tile 128x256, 512 thr = 8 waves 2x4, wave 64x64, BK=32, ring-3 24KB units
// = 72 KB -> 2 blocks/CU, free-run body, 1 barrier/tile, deep-A 2-tile
// cover, mid-tile vmcnt(4)+pack, boundary lgkmcnt(0)+barrier.
// Swizzle both sides: phys_slot = slot ^ ((row>>1)&3), row = 16 u32.
__global__ __launch_bounds__(512, 4) void binlin_fused3(
    const float* __restrict__ x, const uint32_t* __restrict__ wb,
    const float* __restrict__ bias, float* __restrict__ out) {
  __shared__ uint32_t lds[NRING * UNIT_U32];  // 72 KB

  const int tid = threadIdx.x;

  // bijective XCD swizzle (grid=1024): 4 n-blocks of an m-panel -> same L2
  const int per = gridDim.x >> 3;
  const int logical = (blockIdx.x & 7) * per + (blockIdx.x >> 3);
  const int mIdx = logical >> 2;  // N_DIM/BN = 4
  const int nIdx = logical & 3;
  const int row0 = mIdx * BM;
  const int col0 = nIdx * BN;

  const int w8 = tid >> 6;
  const int lane = tid & 63;

  // ---- A reg-staging: wave w8 covers rows [w8*16, w8*16+16) ----
  const int arow = w8 * 16 + (lane >> 2);       // local row 0..127
  const int aslot = lane & 3;                   // logical 16B k-slot
  const float* ga = x + (size_t)(row0 + arow) * K_DIM + aslot * 8;
  const int awidx = arow * 16 + ((aslot ^ ((arow >> 1) & 3)) * 4);

  // ---- B staging via global_load_lds: wave w8 rows [w8*32, +32), 2 ops ----
  const int rl = lane >> 2;
  const int sl = (lane & 3) ^ ((lane >> 3) & 3);  // pre-swizzled source slot
  const uint32_t* gb_base =
      wb + (size_t)(col0 + w8 * 32 + rl) * (K_DIM / 2) + sl * 4;

  // ---- compute indices (wave 64x64) ----
  const int wr = w8 >> 2;   // 0..1
  const int wc = w8 & 3;    // 0..3
  const int cl = lane & 15;
  const int kg = lane >> 4;

  f32x4 acc[4][4] = {};
  bf16x8 af[4], bfr[2];
  f32x4 XA0, XA1, YA0, YA1;  // two A fp32 sets in flight (8 floats each)

#define STAGE_B1(kt, SD, c)                                               \
  __builtin_amdgcn_global_load_lds(                                       \
      (const AS1 uint32_t*)(gb_base + (size_t)((c)*16) * (K_DIM / 2) +    \
                            (kt)*16),                                     \
      (AS3 uint32_t*)((SD) + AOFF_U32 + (w8 * 32 + (c)*16) * 16), 16, 0, 0)

#define LOAD_A2(kt, R0, R1)                                   \
  do {                                                        \
    const f32x4* pa = (const f32x4*)(ga + (size_t)(kt) * 32); \
    R0 = pa[0];                                               \
    R1 = pa[1];                                               \
  } while (0)

#define PACK_A(SD, R0, R1)                                                \
  do {                                                                    \
    u32x4 pk = {pack_bf16(R0[0], R0[1]), pack_bf16(R0[2], R0[3]),         \
                pack_bf16(R1[0], R1[1]), pack_bf16(R1[2], R1[3])};        \
    *(u32x4*)((SD) + awidx) = pk;                                         \
  } while (0)

#define READ_AF(AB)                                                            \
  _Pragma("unroll") for (int m = 0; m < 4; ++m) {                              \
    int rr = wr * 64 + m * 16 + cl;                                            \
    af[m] =                                                                    \
        *(const bf16x8*)((AB) + rr * 16 + ((kg ^ ((rr >> 1) & 3)) * 4));       \
  }

#define READ_BF(BB, NH)                                                        \
  _Pragma("unroll") for (int n = 0; n < 2; ++n) {                              \
    int rr = wc * 64 + ((NH)*2 + n) * 16 + cl;                                 \
    bfr[n] =                                                                   \
        *(const bf16x8*)((BB) + rr * 16 + ((kg ^ ((rr >> 1) & 3)) * 4));       \
  }

#define MFMA_CL(NH)                                                            \
  _Pragma("unroll") for (int m = 0; m < 4; ++m)                                \
  _Pragma("unroll") for (int n = 0; n < 2; ++n)                                \
  acc[m][(NH)*2 + n] = __builtin_amdgcn_mfma_f32_16x16x32_bf16(                \
      af[m], bfr[n], acc[m][(NH)*2 + n], 0, 0, 0);

  // TILE(t): compute unit cu=t%3; stage B(t+2)->su=(t+2)%3; load A(t+3)->L;
  // mid-tile vmcnt(MIDN) + pack A(t+2) (set P) -> su; boundary lgkm+barrier.
#define TILE(DOB, DOA, MIDN, DOPACK, DOBAR, P0, P1, L0, L1, TB, TA)       \
  do {                                                                    \
    const uint32_t* AB = &lds[cu * UNIT_U32];                             \
    const uint32_t* BB = AB + AOFF_U32;                                   \
    uint32_t* SD = &lds[su * UNIT_U32];                                   \
    if (DOB) {                                                            \
      STAGE_B1((TB), SD, 0);                                              \
      STAGE_B1((TB), SD, 1);                                              \
    }                                                                     \
    if (DOA) LOAD_A2((TA), L0, L1);                                       \
    READ_AF(AB);                                                          \
    READ_BF(BB, 0);                                                       \
    MFMA_CL(0);                                                           \
    asm volatile("s_waitcnt vmcnt(" #MIDN ")" ::: "memory");              \
    if (DOPACK) PACK_A(SD, P0, P1);                                       \
    READ_BF(BB, 1);                                                       \
    MFMA_CL(1);                                                           \
    if (DOBAR) {                                                          \
      asm volatile("s_waitcnt lgkmcnt(0)" ::: "memory");                  \
      __builtin_amdgcn_s_barrier();                                       \
    }                                                                     \
    cu = (cu == NRING - 1) ? 0 : cu + 1;                                  \
    su = (su == NRING - 1) ? 0 : su + 1;                                  \
  } while (0)

  // ---- prologue ----
  // FIFO target entering tile 0: [B(1) 2, A(2) 2].
  {
    f32x4 T00, T01, T10, T11;
    LOAD_A2(0, T00, T01);
    LOAD_A2(1, T10, T11);
    STAGE_B1(0, &lds[0], 0);
    STAGE_B1(0, &lds[0], 1);
    STAGE_B1(1, &lds[UNIT_U32], 0);
    STAGE_B1(1, &lds[UNIT_U32], 1);
    PACK_A(&lds[0], T00, T01);           // auto-waits A(0)
    PACK_A(&lds[UNIT_U32], T10, T11);    // auto-waits A(1)
    LOAD_A2(2, XA0, XA1);                // A(2) -> X, stays in flight
    asm volatile("s_waitcnt vmcnt(4)" ::: "memory");  // retire B(0); keep B(1)+A(2)
    asm volatile("s_waitcnt lgkmcnt(0)" ::: "memory");
    __builtin_amdgcn_s_barrier();
  }

  int cu = 0, su = 2;
  // steady tiles t = 0..27 (even count), unroll-2 for A-set parity:
  // even t: pack X (=A(t+2)), load Y (<-A(t+3)); odd t: reverse.
  for (int t2 = 0; t2 < 28; t2 += 2) {
    TILE(1, 1, 4, 1, 1, XA0, XA1, YA0, YA1, t2 + 2, t2 + 3);
    TILE(1, 1, 4, 1, 1, YA0, YA1, XA0, XA1, t2 + 3, t2 + 4);
  }
  // t=28 (even, steady): B(30), A(31)->Y, pack X=A(30)
  TILE(1, 1, 4, 1, 1, XA0, XA1, YA0, YA1, 30, 31);
  // t=29 (odd): B(31), no A-load, vmcnt(2), pack Y=A(31)
  TILE(1, 0, 2, 1, 1, YA0, YA1, XA0, XA1, 31, 0);
  // t=30: nothing to issue, vmcnt(0), no pack
  TILE(0, 0, 0, 0, 1, XA0, XA1, YA0, YA1, 0, 0);
  // t=31: compute only
  TILE(0, 0, 0, 0, 0, XA0, XA1, YA0, YA1, 0, 0);

  // ---- epilogue: bias + fp32 store ----
#pragma unroll
  for (int n = 0; n < 4; ++n) {
    int col = col0 + wc * 64 + n * 16 + cl;
    float bv = bias[col];
#pragma unroll
    for (int m = 0; m < 4; ++m) {
      int rowb = row0 + wr * 64 + m * 16 + kg * 4;
#pragma unroll
      for (int i = 0; i < 4; ++i) {
        out[(size_t)(rowb + i) * N_DIM + col] = acc[m][n][i] + bv;
      }
    }
  }
#undef STAGE_B1
#undef LOAD_A2
#undef PACK_A
#undef READ_AF
#undef READ_BF
#undef MFMA_CL
#undef TILE
}

extern "C" void kernel_launch(void* const* d_in, const int* in_sizes, int n_in,
                              void* d_out, int out_size, void* d_ws, size_t ws_size,
                              hipStream_t stream) {
  const float* x = (const float*)d_in[0];
  const float* w = (const float*)d_in[1];
  const float* bias = (const float*)d_in[2];
  const float* kk = (const float*)d_in[3];
  const float* aa = (const float*)d_in[4];
  float* out = (float*)d_out;

  uint32_t* wb = (uint32_t*)d_ws;  // 2 MB bf16 w_bin
  wconv<<<(N_DIM * K_DIM) / (256 * 16), 256, 0, stream>>>(w, kk, aa, wb);

  const int M = in_sizes[0] / K_DIM;         // 32768
  const int grid = (M / BM) * (N_DIM / BN);  // 256 * 4 = 1024
  binlin_fused3<<<grid, 512, 0, stream>>>(x, wb, bias, out);
}

// Round 23
// 106.924 us; speedup vs baseline: 1.3579x; 1.3579x over previous
//
#include <hip/hip_runtime.h>
#include <stdint.h>

#define K_DIM 1024
#define N_DIM 1024
#define BM 128
#define BN 256
#define BK 32
#define NT (K_DIM / BK)             // 32 K-tiles
#define AOFF_U32 (BM * 16)          // A region: 128 rows x 16 u32
#define UNIT_U32 ((BM + BN) * 16)   // 24 KB per ring unit
#define NRING 3                     // 72 KB -> 2 blocks/CU

#define AS1 __attribute__((address_space(1)))
#define AS3 __attribute__((address_space(3)))

typedef __attribute__((ext_vector_type(4))) float f32x4;
typedef __attribute__((ext_vector_type(8))) short bf16x8;
typedef __attribute__((ext_vector_type(4))) uint32_t u32x4;

// round-half-up to bf16, pack two: low 16 = a, high 16 = b
__device__ __forceinline__ uint32_t pack_bf16(float a, float b) {
  uint32_t ua = __builtin_bit_cast(uint32_t, a) + 0x8000u;
  uint32_t ub = __builtin_bit_cast(uint32_t, b) + 0x8000u;
  return __builtin_amdgcn_perm(ub, ua, 0x07060302u);
}

__device__ __forceinline__ float wbin1(float v, float kkv, float aav) {
  float t = v * kkv;
  t = fminf(fmaxf(t, -1.0f), 1.0f);
  return t * aav;
}

// ---------------- kernel 1: w_bin = bf16(aa*clamp(kk*w,-1,1)) into ws ------
__global__ __launch_bounds__(256) void wconv(const float* __restrict__ w,
                                             const float* __restrict__ kkp,
                                             const float* __restrict__ aap,
                                             uint32_t* __restrict__ wb) {
  const float kkv = kkp[0];
  const float aav = aap[0];
  const int g = blockIdx.x * 256 + threadIdx.x;  // 16 floats per thread
  const f32x4* src = (const f32x4*)(w + (size_t)g * 16);
  f32x4 v0 = src[0], v1 = src[1], v2 = src[2], v3 = src[3];
  uint32_t p[8];
#pragma unroll
  for (int i = 0; i < 4; ++i) {
    f32x4 v = i == 0 ? v0 : (i == 1 ? v1 : (i == 2 ? v2 : v3));
    p[2 * i] = pack_bf16(wbin1(v[0], kkv, aav), wbin1(v[1], kkv, aav));
    p[2 * i + 1] = pack_bf16(wbin1(v[2], kkv, aav), wbin1(v[3], kkv, aav));
  }
  u32x4* dst = (u32x4*)(wb + (size_t)g * 8);
  dst[0] = u32x4{p[0], p[1], p[2], p[3]};
  dst[1] = u32x4{p[4], p[5], p[6], p[7]};
}

// ---------------- kernel 2: fused-convert ring-3, deep-A free-run GEMM -----
// SESSION CHAMPION (R16, 108.3 us bench). Tile 128x256, 512 thr = 8 waves
// 2x4, wave 64x64, BK=32, ring-3 24KB units = 72 KB -> 2 blocks/CU,
// free-run body, 1 barrier/tile, A-pipeline with TWO tiles of cover:
//   tile t: issue B(t+2) DMA -> unit (t+2)%3; issue A(t+3) fp32 -> reg set L.
//           after MFMA cluster 0: vmcnt(4) retires B(t+1)+A(t+2) ->
//           pack A(t+2) (set P) into unit (t+2)%3 (readers done at barrier
//           t-1). Boundary = lgkmcnt(0) + barrier ONLY.
// Per-wave vmem FIFO entering tile t: [B(t+1) 2, A(t+2) 2]; issue 4 more ->
// mid-tile vmcnt(4) retires exactly the entering 4. Tail: vmcnt 2/0.
// vmcnt never 0 until t=NT-2. Ping-pong A sets, manual unroll-2 (rule #20).
// Swizzle both sides: phys_slot = slot ^ ((row>>1)&3), row = 16 u32.
// NOTE: s_setprio(1) around MFMA clusters is a PROTECTED feature — R22 A/B
// measured removing it costs ~27% (free-run waves have role diversity, so
// T5 arbitration pays here, unlike lockstep structures/m190).
__global__ __launch_bounds__(512, 4) void binlin_fused3(
    const float* __restrict__ x, const uint32_t* __restrict__ wb,
    const float* __restrict__ bias, float* __restrict__ out) {
  __shared__ uint32_t lds[NRING * UNIT_U32];  // 72 KB

  const int tid = threadIdx.x;

  // bijective XCD swizzle (grid=1024): 4 n-blocks of an m-panel -> same L2
  const int per = gridDim.x >> 3;
  const int logical = (blockIdx.x & 7) * per + (blockIdx.x >> 3);
  const int mIdx = logical >> 2;  // N_DIM/BN = 4
  const int nIdx = logical & 3;
  const int row0 = mIdx * BM;
  const int col0 = nIdx * BN;

  const int w8 = tid >> 6;
  const int lane = tid & 63;

  // ---- A reg-staging: wave w8 covers rows [w8*16, w8*16+16) ----
  const int arow = w8 * 16 + (lane >> 2);       // local row 0..127
  const int aslot = lane & 3;                   // logical 16B k-slot
  const float* ga = x + (size_t)(row0 + arow) * K_DIM + aslot * 8;
  const int awidx = arow * 16 + ((aslot ^ ((arow >> 1) & 3)) * 4);

  // ---- B staging via global_load_lds: wave w8 rows [w8*32, +32), 2 ops ----
  const int rl = lane >> 2;
  const int sl = (lane & 3) ^ ((lane >> 3) & 3);  // pre-swizzled source slot
  const uint32_t* gb_base =
      wb + (size_t)(col0 + w8 * 32 + rl) * (K_DIM / 2) + sl * 4;

  // ---- compute indices (wave 64x64) ----
  const int wr = w8 >> 2;   // 0..1
  const int wc = w8 & 3;    // 0..3
  const int cl = lane & 15;
  const int kg = lane >> 4;

  f32x4 acc[4][4] = {};
  bf16x8 af[4], bfr[2];
  f32x4 XA0, XA1, YA0, YA1;  // two A fp32 sets in flight (8 floats each)

#define STAGE_B1(kt, SD, c)                                               \
  __builtin_amdgcn_global_load_lds(                                       \
      (const AS1 uint32_t*)(gb_base + (size_t)((c)*16) * (K_DIM / 2) +    \
                            (kt)*16),                                     \
      (AS3 uint32_t*)((SD) + AOFF_U32 + (w8 * 32 + (c)*16) * 16), 16, 0, 0)

#define LOAD_A2(kt, R0, R1)                                   \
  do {                                                        \
    const f32x4* pa = (const f32x4*)(ga + (size_t)(kt) * 32); \
    R0 = pa[0];                                               \
    R1 = pa[1];                                               \
  } while (0)

#define PACK_A(SD, R0, R1)                                                \
  do {                                                                    \
    u32x4 pk = {pack_bf16(R0[0], R0[1]), pack_bf16(R0[2], R0[3]),         \
                pack_bf16(R1[0], R1[1]), pack_bf16(R1[2], R1[3])};        \
    *(u32x4*)((SD) + awidx) = pk;                                         \
  } while (0)

#define READ_AF(AB)                                                            \
  _Pragma("unroll") for (int m = 0; m < 4; ++m) {                              \
    int rr = wr * 64 + m * 16 + cl;                                            \
    af[m] =                                                                    \
        *(const bf16x8*)((AB) + rr * 16 + ((kg ^ ((rr >> 1) & 3)) * 4));       \
  }

#define READ_BF(BB, NH)                                                        \
  _Pragma("unroll") for (int n = 0; n < 2; ++n) {                              \
    int rr = wc * 64 + ((NH)*2 + n) * 16 + cl;                                 \
    bfr[n] =                                                                   \
        *(const bf16x8*)((BB) + rr * 16 + ((kg ^ ((rr >> 1) & 3)) * 4));       \
  }

#define MFMA_CL(NH)                                                            \
  __builtin_amdgcn_s_setprio(1);                                               \
  _Pragma("unroll") for (int m = 0; m < 4; ++m)                                \
  _Pragma("unroll") for (int n = 0; n < 2; ++n)                                \
  acc[m][(NH)*2 + n] = __builtin_amdgcn_mfma_f32_16x16x32_bf16(                \
      af[m], bfr[n], acc[m][(NH)*2 + n], 0, 0, 0);                             \
  __builtin_amdgcn_s_setprio(0);

  // TILE(t): compute unit cu=t%3; stage B(t+2)->su=(t+2)%3; load A(t+3)->L;
  // mid-tile vmcnt(MIDN) + pack A(t+2) (set P) -> su; boundary lgkm+barrier.
#define TILE(DOB, DOA, MIDN, DOPACK, DOBAR, P0, P1, L0, L1, TB, TA)       \
  do {                                                                    \
    const uint32_t* AB = &lds[cu * UNIT_U32];                             \
    const uint32_t* BB = AB + AOFF_U32;                                   \
    uint32_t* SD = &lds[su * UNIT_U32];                                   \
    if (DOB) {                                                            \
      STAGE_B1((TB), SD, 0);                                              \
      STAGE_B1((TB), SD, 1);                                              \
    }                                                                     \
    if (DOA) LOAD_A2((TA), L0, L1);                                       \
    READ_AF(AB);                                                          \
    READ_BF(BB, 0);                                                       \
    MFMA_CL(0);                                                           \
    asm volatile("s_waitcnt vmcnt(" #MIDN ")" ::: "memory");              \
    if (DOPACK) PACK_A(SD, P0, P1);                                       \
    READ_BF(BB, 1);                                                       \
    MFMA_CL(1);                                                           \
    if (DOBAR) {                                                          \
      asm volatile("s_waitcnt lgkmcnt(0)" ::: "memory");                  \
      __builtin_amdgcn_s_barrier();                                       \
    }                                                                     \
    cu = (cu == NRING - 1) ? 0 : cu + 1;                                  \
    su = (su == NRING - 1) ? 0 : su + 1;                                  \
  } while (0)

  // ---- prologue ----
  // FIFO target entering tile 0: [B(1) 2, A(2) 2].
  {
    f32x4 T00, T01, T10, T11;
    LOAD_A2(0, T00, T01);
    LOAD_A2(1, T10, T11);
    STAGE_B1(0, &lds[0], 0);
    STAGE_B1(0, &lds[0], 1);
    STAGE_B1(1, &lds[UNIT_U32], 0);
    STAGE_B1(1, &lds[UNIT_U32], 1);
    PACK_A(&lds[0], T00, T01);           // auto-waits A(0)
    PACK_A(&lds[UNIT_U32], T10, T11);    // auto-waits A(1)
    LOAD_A2(2, XA0, XA1);                // A(2) -> X, stays in flight
    asm volatile("s_waitcnt vmcnt(4)" ::: "memory");  // retire B(0); keep B(1)+A(2)
    asm volatile("s_waitcnt lgkmcnt(0)" ::: "memory");
    __builtin_amdgcn_s_barrier();
  }

  int cu = 0, su = 2;
  // steady tiles t = 0..27 (even count), unroll-2 for A-set parity:
  // even t: pack X (=A(t+2)), load Y (<-A(t+3)); odd t: reverse.
  for (int t2 = 0; t2 < 28; t2 += 2) {
    TILE(1, 1, 4, 1, 1, XA0, XA1, YA0, YA1, t2 + 2, t2 + 3);
    TILE(1, 1, 4, 1, 1, YA0, YA1, XA0, XA1, t2 + 3, t2 + 4);
  }
  // t=28 (even, steady): B(30), A(31)->Y, pack X=A(30)
  TILE(1, 1, 4, 1, 1, XA0, XA1, YA0, YA1, 30, 31);
  // t=29 (odd): B(31), no A-load, vmcnt(2), pack Y=A(31)
  TILE(1, 0, 2, 1, 1, YA0, YA1, XA0, XA1, 31, 0);
  // t=30: nothing to issue, vmcnt(0), no pack
  TILE(0, 0, 0, 0, 1, XA0, XA1, YA0, YA1, 0, 0);
  // t=31: compute only
  TILE(0, 0, 0, 0, 0, XA0, XA1, YA0, YA1, 0, 0);

  // ---- epilogue: bias + fp32 store ----
#pragma unroll
  for (int n = 0; n < 4; ++n) {
    int col = col0 + wc * 64 + n * 16 + cl;
    float bv = bias[col];
#pragma unroll
    for (int m = 0; m < 4; ++m) {
      int rowb = row0 + wr * 64 + m * 16 + kg * 4;
#pragma unroll
      for (int i = 0; i < 4; ++i) {
        out[(size_t)(rowb + i) * N_DIM + col] = acc[m][n][i] + bv;
      }
    }
  }
#undef STAGE_B1
#undef LOAD_A2
#undef PACK_A
#undef READ_AF
#undef READ_BF
#undef MFMA_CL
#undef TILE
}

extern "C" void kernel_launch(void* const* d_in, const int* in_sizes, int n_in,
                              void* d_out, int out_size, void* d_ws, size_t ws_size,
                              hipStream_t stream) {
  const float* x = (const float*)d_in[0];
  const float* w = (const float*)d_in[1];
  const float* bias = (const float*)d_in[2];
  const float* kk = (const float*)d_in[3];
  const float* aa = (const float*)d_in[4];
  float* out = (float*)d_out;

  uint32_t* wb = (uint32_t*)d_ws;  // 2 MB bf16 w_bin
  wconv<<<(N_DIM * K_DIM) / (256 * 16), 256, 0, stream>>>(w, kk, aa, wb);

  const int M = in_sizes[0] / K_DIM;         // 32768
  const int grid = (M / BM) * (N_DIM / BN);  // 256 * 4 = 1024
  binlin_fused3<<<grid, 512, 0, stream>>>(x, wb, bias, out);
}